// Round 2
// baseline (153.686 us; speedup 1.0000x reference)
//
#include <hip/hip_runtime.h>
#include <hip/hip_bf16.h>
#include <stdint.h>

#define B_N 65536
#define L_N 64
#define E_N 8
#define NS 128
#define MAXT (B_N/NS + E_N)   // 520 max tiles

typedef __attribute__((ext_vector_type(4))) float f32x4;
typedef __attribute__((ext_vector_type(8))) short short8;

__device__ __forceinline__ short f2bf(float f){
  union { float f; unsigned u; } v; v.f = f;
  unsigned r = (v.u + 0x7fffu + ((v.u >> 16) & 1u)) >> 16;  // RNE
  return (short)r;
}

// ---------------- routing ----------------
__global__ void k_hist(const int* __restrict__ labels, unsigned* __restrict__ counts){
  __shared__ unsigned lc[8];
  if(threadIdx.x < 8) lc[threadIdx.x] = 0;
  __syncthreads();
  int i = blockIdx.x * blockDim.x + threadIdx.x;
  if(i < B_N) atomicAdd(&lc[labels[i] & 7], 1u);
  __syncthreads();
  if(threadIdx.x < 8 && lc[threadIdx.x]) atomicAdd(&counts[threadIdx.x], lc[threadIdx.x]);
}

__global__ void k_scan(const unsigned* __restrict__ counts, unsigned* __restrict__ cursor,
                       int* __restrict__ te, int* __restrict__ tb, int* __restrict__ tl){
  __shared__ int off[9], ts[9];
  if(threadIdx.x == 0){
    int o = 0, t = 0;
    for(int e=0;e<8;e++){
      off[e] = o; ts[e] = t;
      o += (int)counts[e];
      t += ((int)counts[e] + NS - 1) / NS;
    }
    off[8] = o; ts[8] = t;
    for(int e=0;e<8;e++) cursor[e] = (unsigned)off[e];
  }
  __syncthreads();
  for(int i = threadIdx.x; i < MAXT; i += blockDim.x){
    if(i < ts[8]){
      int e = 0;
      while(e < 7 && i >= ts[e+1]) e++;
      te[i] = e;
      tb[i] = off[e] + (i - ts[e]) * NS;
      tl[i] = off[e] + (int)counts[e];
    } else { te[i] = 0; tb[i] = 0; tl[i] = 0; }
  }
}

__global__ void k_scatter(const int* __restrict__ labels, unsigned* __restrict__ cursor,
                          int* __restrict__ perm){
  __shared__ unsigned lcnt[8], lbase[8];
  if(threadIdx.x < 8) lcnt[threadIdx.x] = 0;
  __syncthreads();
  int i = blockIdx.x * blockDim.x + threadIdx.x;
  int e = 0; unsigned r = 0;
  if(i < B_N){ e = labels[i] & 7; r = atomicAdd(&lcnt[e], 1u); }
  __syncthreads();
  if(threadIdx.x < 8 && lcnt[threadIdx.x])
    lbase[threadIdx.x] = atomicAdd(&cursor[threadIdx.x], lcnt[threadIdx.x]);
  __syncthreads();
  if(i < B_N) perm[lbase[e] + r] = i;
}

// ---------------- weight fragment prep ----------------
// frag layout per (expert, kstep): [t 0..15][lane 0..63][j 0..7] bf16 (16B/lane)
// A-frag element (lane l, j): out_f m = 16t + (l&15); k = 32s + 4(l>>4) + (j&3) + 16(j>>2)
__global__ void k_pw(const float* __restrict__ W0, const float* __restrict__ Wh,
                     short* __restrict__ wf0, short* __restrict__ wf1){
  int uid = blockIdx.x * blockDim.x + threadIdx.x;
  const int NU0 = 8*3*16*64;       // 24576
  const int NU1 = 2*8*8*16*64;     // 131072
  if(uid < NU0){
    int e = uid / 3072, r = uid % 3072;
    int s = r / 1024, r2 = r % 1024, t = r2 / 64, l = r2 % 64;
    int g = l >> 4, m = 16*t + (l & 15);
    short8 v;
    #pragma unroll
    for(int j=0;j<8;j++){
      int k = 32*s + 4*g + (j & 3) + 16*(j >> 2);
      float f = (k < 67) ? W0[(e*67 + k)*256 + m] : 0.f;
      v[j] = f2bf(f);
    }
    *(short8*)(wf0 + (size_t)uid * 8) = v;
  } else if(uid < NU0 + NU1){
    int u = uid - NU0;
    int lh = u / 65536, r = u % 65536;
    int e = r / 8192, r1 = r % 8192;
    int s = r1 / 1024, r2 = r1 % 1024, t = r2 / 64, l = r2 % 64;
    int g = l >> 4, m = 16*t + (l & 15);
    short8 v;
    #pragma unroll
    for(int j=0;j<8;j++){
      int k = 32*s + 4*g + (j & 3) + 16*(j >> 2);
      v[j] = f2bf(Wh[(((size_t)(lh*8 + e))*256 + k)*256 + m]);
    }
    *(short8*)(wf1 + (size_t)u * 8) = v;
  }
}

// ---------------- fused MoE MLP (barrier-free, weights streamed from L1/L2) ----------------
__device__ __forceinline__ void relu_repack(f32x4* acc, const float* bias, int g, short8* hb){
  #pragma unroll
  for(int t=0;t<16;t++){
    f32x4 b4 = *(const f32x4*)(bias + 16*t + 4*g);
    #pragma unroll
    for(int r=0;r<4;r++){
      float vv = acc[t][r] + b4[r];
      acc[t][r] = vv > 0.f ? vv : 0.f;
    }
  }
  #pragma unroll
  for(int s=0;s<8;s++){
    short8 h;
    #pragma unroll
    for(int r=0;r<4;r++){ h[r] = f2bf(acc[2*s][r]); h[4+r] = f2bf(acc[2*s+1][r]); }
    hb[s] = h;
  }
  #pragma unroll
  for(int t=0;t<16;t++) acc[t] = (f32x4){0.f,0.f,0.f,0.f};
}

__device__ __forceinline__ float out_dot(f32x4* acc, const float* bias, const float* wo, int g){
  float dot = 0.f;
  #pragma unroll
  for(int t=0;t<16;t++){
    f32x4 b4 = *(const f32x4*)(bias + 16*t + 4*g);
    f32x4 w4 = *(const f32x4*)(wo + 16*t + 4*g);
    #pragma unroll
    for(int r=0;r<4;r++){
      float vv = acc[t][r] + b4[r];
      vv = vv > 0.f ? vv : 0.f;
      dot += vv * w4[r];
    }
  }
  dot += __shfl_xor(dot, 16, 64);
  dot += __shfl_xor(dot, 32, 64);
  return dot;
}

__global__ __launch_bounds__(256, 2) void k_mlp(
    const float* __restrict__ x, const float* __restrict__ eps,
    const float* __restrict__ mu_t, const float* __restrict__ lv_t,
    const float* __restrict__ b0, const float* __restrict__ bh,
    const float* __restrict__ Wo, const float* __restrict__ bo,
    const short* __restrict__ wf0, const short* __restrict__ wf1,
    const int* __restrict__ perm, const int* __restrict__ te,
    const int* __restrict__ tb, const int* __restrict__ tl,
    float* __restrict__ out)
{
  const int tid = threadIdx.x;
  const int w = tid >> 6, lane = tid & 63;
  const int g = lane >> 4, col = lane & 15;
  const int bid = blockIdx.x;
  const int e = te[bid], base = tb[bid], lim = tl[bid];
  if(base >= lim) return;

  // two sample sets per wave: 32 samples/wave, 128/block
  const int pos0 = base + w*32 + col;
  const int pos1 = pos0 + 16;
  const bool v0 = pos0 < lim, v1 = pos1 < lim;
  const int sid0 = perm[v0 ? pos0 : (lim - 1)];
  const int sid1 = perm[v1 ? pos1 : (lim - 1)];
  const float bo_e = bo[e];

  // ---- layer-0 B-fragments (x_in^T), built per-lane from gathered inputs ----
  short8 bx0[3], bx1[3];
  #pragma unroll
  for(int s=0;s<3;s++){
    short8 va, vb;
    #pragma unroll
    for(int jh=0;jh<2;jh++){
      #pragma unroll
      for(int q=0;q<4;q++){
        int k = 32*s + 4*g + 16*jh + q;
        float fa = 0.f, fb = 0.f;
        if(k < 3){ fa = x[sid0*3 + k]; fb = x[sid1*3 + k]; }
        else if(k < 67){
          int zi = k - 3;
          float m = mu_t[e*64 + zi], sd = __expf(0.5f * lv_t[e*64 + zi]);
          fa = m + eps[(size_t)sid0*64 + zi] * sd;
          fb = m + eps[(size_t)sid1*64 + zi] * sd;
        }
        va[jh*4 + q] = f2bf(fa);
        vb[jh*4 + q] = f2bf(fb);
      }
    }
    bx0[s] = va; bx1[s] = vb;
  }

  const short* w0e = wf0 + (size_t)e * (3*8192);
  const short* w1e = wf1 + (size_t)e * (8*8192);
  const short* w2e = wf1 + (size_t)(8 + e) * (8*8192);

  f32x4 acc0[16], acc1[16];
  #pragma unroll
  for(int t=0;t<16;t++){ acc0[t] = (f32x4){0.f,0.f,0.f,0.f}; acc1[t] = (f32x4){0.f,0.f,0.f,0.f}; }
  short8 hb0[8], hb1[8];

  // ---- layer 0: K = 96 (3 ksteps) ----
  #pragma unroll
  for(int ks=0; ks<3; ks++){
    const short* fb = w0e + ks*8192;
    #pragma unroll
    for(int t=0;t<16;t++){
      short8 a = *(const short8*)(fb + t*512 + lane*8);
      acc0[t] = __builtin_amdgcn_mfma_f32_16x16x32_bf16(a, bx0[ks], acc0[t], 0, 0, 0);
      acc1[t] = __builtin_amdgcn_mfma_f32_16x16x32_bf16(a, bx1[ks], acc1[t], 0, 0, 0);
    }
  }
  relu_repack(acc0, b0 + e*256, g, hb0);
  relu_repack(acc1, b0 + e*256, g, hb1);

  // ---- layer 1: K = 256 (8 ksteps) ----
  #pragma unroll
  for(int ks=0; ks<8; ks++){
    const short* fb = w1e + ks*8192;
    #pragma unroll
    for(int t=0;t<16;t++){
      short8 a = *(const short8*)(fb + t*512 + lane*8);
      acc0[t] = __builtin_amdgcn_mfma_f32_16x16x32_bf16(a, hb0[ks], acc0[t], 0, 0, 0);
      acc1[t] = __builtin_amdgcn_mfma_f32_16x16x32_bf16(a, hb1[ks], acc1[t], 0, 0, 0);
    }
  }
  relu_repack(acc0, bh + (0*8 + e)*256, g, hb0);
  relu_repack(acc1, bh + (0*8 + e)*256, g, hb1);

  // ---- layer 2: K = 256 (8 ksteps) ----
  #pragma unroll
  for(int ks=0; ks<8; ks++){
    const short* fb = w2e + ks*8192;
    #pragma unroll
    for(int t=0;t<16;t++){
      short8 a = *(const short8*)(fb + t*512 + lane*8);
      acc0[t] = __builtin_amdgcn_mfma_f32_16x16x32_bf16(a, hb0[ks], acc0[t], 0, 0, 0);
      acc1[t] = __builtin_amdgcn_mfma_f32_16x16x32_bf16(a, hb1[ks], acc1[t], 0, 0, 0);
    }
  }

  // ---- output layer ----
  float d0 = out_dot(acc0, bh + (1*8 + e)*256, Wo + e*256, g);
  float d1 = out_dot(acc1, bh + (1*8 + e)*256, Wo + e*256, g);
  if(g == 0 && v0) out[sid0] = d0 + bo_e;
  if(g == 0 && v1) out[sid1] = d1 + bo_e;
}

// ---------------- KL ----------------
__global__ void k_kl(const float* __restrict__ mu_t, const float* __restrict__ lv_t,
                     const unsigned* __restrict__ counts, float* __restrict__ klout){
  __shared__ float fe[8];
  int t = threadIdx.x;
  if(t < 8){
    float s = 0.f;
    for(int i=0;i<64;i++){
      float m = mu_t[t*64+i], l = lv_t[t*64+i];
      s += 1.f + l - m*m - expf(l);
    }
    fe[t] = s;
  }
  __syncthreads();
  if(t == 0){
    float kl = 0.f;
    for(int e=0;e<8;e++) kl += fe[e] * (float)counts[e];
    klout[0] = -0.5f * kl / (float)B_N;
  }
}

extern "C" void kernel_launch(void* const* d_in, const int* in_sizes, int n_in,
                              void* d_out, int out_size, void* d_ws, size_t ws_size,
                              hipStream_t stream){
  (void)in_sizes; (void)n_in; (void)out_size; (void)ws_size;
  const float* x   = (const float*)d_in[0];
  const int*   lab = (const int*)d_in[1];
  const float* eps = (const float*)d_in[2];
  const float* mu  = (const float*)d_in[3];
  const float* lv  = (const float*)d_in[4];
  const float* W0  = (const float*)d_in[5];
  const float* b0  = (const float*)d_in[6];
  const float* Wh  = (const float*)d_in[7];
  const float* bh  = (const float*)d_in[8];
  const float* Wo  = (const float*)d_in[9];
  const float* bo  = (const float*)d_in[10];
  float* out = (float*)d_out;

  char* ws = (char*)d_ws;
  unsigned* counts = (unsigned*)(ws + 0);
  unsigned* cursor = (unsigned*)(ws + 32);
  int* te   = (int*)(ws + 128);
  int* tb   = (int*)(ws + 128 + 4*MAXT);
  int* tl   = (int*)(ws + 128 + 8*MAXT);
  int* perm = (int*)(ws + 12544);
  short* wf0 = (short*)(ws + 275456);   // 8 experts x 3 ksteps x 16KB
  short* wf1 = (short*)(ws + 668672);   // 2 layers x 8 experts x 8 ksteps x 16KB

  hipMemsetAsync(ws, 0, 64, stream);  // counts + cursor
  k_hist<<<256, 256, 0, stream>>>(lab, counts);
  k_scan<<<1, 256, 0, stream>>>(counts, cursor, te, tb, tl);
  k_scatter<<<256, 256, 0, stream>>>(lab, cursor, perm);
  k_pw<<<(24576 + 131072 + 255)/256, 256, 0, stream>>>(W0, Wh, wf0, wf1);
  k_mlp<<<MAXT, 256, 0, stream>>>(x, eps, mu, lv, b0, bh, Wo, bo,
                                  wf0, wf1, perm, te, tb, tl, out);
  k_kl<<<1, 64, 0, stream>>>(mu, lv, counts, out + B_N);
}

// Round 3
// 108.013 us; speedup vs baseline: 1.4228x; 1.4228x over previous
//
#include <hip/hip_runtime.h>
#include <hip/hip_bf16.h>
#include <stdint.h>

#define B_N 65536
#define L_N 64
#define E_N 8
#define NS 128
#define MAXT (B_N/NS + E_N)   // 520 max tiles

typedef __attribute__((ext_vector_type(4))) float f32x4;
typedef __attribute__((ext_vector_type(16))) float f32x16;
typedef __attribute__((ext_vector_type(8))) short short8;

__device__ __forceinline__ short f2bf(float f){
  union { float f; unsigned u; } v; v.f = f;
  unsigned r = (v.u + 0x7fffu + ((v.u >> 16) & 1u)) >> 16;  // RNE
  return (short)r;
}

// ---------------- routing ----------------
__global__ void k_hist(const int* __restrict__ labels, unsigned* __restrict__ counts){
  __shared__ unsigned lc[8];
  if(threadIdx.x < 8) lc[threadIdx.x] = 0;
  __syncthreads();
  int i = blockIdx.x * blockDim.x + threadIdx.x;
  if(i < B_N) atomicAdd(&lc[labels[i] & 7], 1u);
  __syncthreads();
  if(threadIdx.x < 8 && lc[threadIdx.x]) atomicAdd(&counts[threadIdx.x], lc[threadIdx.x]);
}

__global__ void k_scan(const unsigned* __restrict__ counts, unsigned* __restrict__ cursor,
                       int* __restrict__ te, int* __restrict__ tb, int* __restrict__ tl){
  __shared__ int off[9], ts[9];
  if(threadIdx.x == 0){
    int o = 0, t = 0;
    for(int e=0;e<8;e++){
      off[e] = o; ts[e] = t;
      o += (int)counts[e];
      t += ((int)counts[e] + NS - 1) / NS;
    }
    off[8] = o; ts[8] = t;
    for(int e=0;e<8;e++) cursor[e] = (unsigned)off[e];
  }
  __syncthreads();
  for(int i = threadIdx.x; i < MAXT; i += blockDim.x){
    if(i < ts[8]){
      int e = 0;
      while(e < 7 && i >= ts[e+1]) e++;
      te[i] = e;
      tb[i] = off[e] + (i - ts[e]) * NS;
      tl[i] = off[e] + (int)counts[e];
    } else { te[i] = 0; tb[i] = 0; tl[i] = 0; }
  }
}

__global__ void k_scatter(const int* __restrict__ labels, unsigned* __restrict__ cursor,
                          int* __restrict__ perm){
  __shared__ unsigned lcnt[8], lbase[8];
  if(threadIdx.x < 8) lcnt[threadIdx.x] = 0;
  __syncthreads();
  int i = blockIdx.x * blockDim.x + threadIdx.x;
  int e = 0; unsigned r = 0;
  if(i < B_N){ e = labels[i] & 7; r = atomicAdd(&lcnt[e], 1u); }
  __syncthreads();
  if(threadIdx.x < 8 && lcnt[threadIdx.x])
    lbase[threadIdx.x] = atomicAdd(&cursor[threadIdx.x], lcnt[threadIdx.x]);
  __syncthreads();
  if(i < B_N) perm[lbase[e] + r] = i;
}

// ---------------- weight fragment prep (32x32x16 A-frags) ----------------
// per (expert, kstep16): [t 0..7][lane 0..63][j 0..7] bf16 (16B/lane)
// A elem (lane l, j): m = 32t + (l&31); k = 16s + 4*(l>>5) + (j&3) + 8*(j>>2)
__global__ void k_pw(const float* __restrict__ W0, const float* __restrict__ Wh,
                     short* __restrict__ wf0, short* __restrict__ wf1){
  int uid = blockIdx.x * blockDim.x + threadIdx.x;
  const int NU0 = 8*5*8*64;        // 20480 (layer0: K=67 -> 5 ksteps of 16)
  const int NU1 = 2*8*16*8*64;     // 131072 (hidden: K=256 -> 16 ksteps)
  if(uid < NU0){
    int e = uid / 2560, r = uid % 2560;
    int s = r / 512, r2 = r % 512, t = r2 / 64, l = r2 % 64;
    int hi = l >> 5, m = 32*t + (l & 31);
    short8 v;
    #pragma unroll
    for(int j=0;j<8;j++){
      int k = 16*s + 4*hi + (j & 3) + 8*(j >> 2);
      float f = (k < 67) ? W0[(e*67 + k)*256 + m] : 0.f;
      v[j] = f2bf(f);
    }
    *(short8*)(wf0 + (size_t)uid * 8) = v;
  } else if(uid < NU0 + NU1){
    int u = uid - NU0;
    int le = u / 8192, r1 = u % 8192;           // le = lh*8 + e
    int s = r1 / 512, r2 = r1 % 512, t = r2 / 64, l = r2 % 64;
    int hi = l >> 5, m = 32*t + (l & 31);
    short8 v;
    #pragma unroll
    for(int j=0;j<8;j++){
      int k = 16*s + 4*hi + (j & 3) + 8*(j >> 2);
      v[j] = f2bf(Wh[((size_t)le*256 + k)*256 + m]);
    }
    *(short8*)(wf1 + (size_t)u * 8) = v;
  }
}

// ---------------- fused MoE MLP (barrier-free, 32x32x16, weights via L1/L2) ----------------
__device__ __forceinline__ void relu_repack32(f32x16* acc, const float* __restrict__ bias,
                                              int hi, short8* hb){
  #pragma unroll
  for(int t=0;t<8;t++){
    #pragma unroll
    for(int q=0;q<4;q++){
      f32x4 b4 = *(const f32x4*)(bias + 32*t + 4*hi + 8*q);
      #pragma unroll
      for(int r=0;r<4;r++){
        float vv = acc[t][4*q+r] + b4[r];
        acc[t][4*q+r] = vv > 0.f ? vv : 0.f;
      }
    }
    short8 h0, h1;
    #pragma unroll
    for(int j=0;j<8;j++){ h0[j] = f2bf(acc[t][j]); h1[j] = f2bf(acc[t][8+j]); }
    hb[2*t] = h0; hb[2*t+1] = h1;
    #pragma unroll
    for(int r=0;r<16;r++) acc[t][r] = 0.f;
  }
}

__device__ __forceinline__ float out_dot32(f32x16* acc, const float* __restrict__ bias,
                                           const float* __restrict__ wo, int hi){
  float dot = 0.f;
  #pragma unroll
  for(int t=0;t<8;t++){
    #pragma unroll
    for(int q=0;q<4;q++){
      f32x4 b4 = *(const f32x4*)(bias + 32*t + 4*hi + 8*q);
      f32x4 w4 = *(const f32x4*)(wo + 32*t + 4*hi + 8*q);
      #pragma unroll
      for(int r=0;r<4;r++){
        float vv = acc[t][4*q+r] + b4[r];
        vv = vv > 0.f ? vv : 0.f;
        dot += vv * w4[r];
      }
    }
  }
  dot += __shfl_xor(dot, 32, 64);   // reduce across hi halves
  return dot;
}

__global__ __launch_bounds__(256, 2) void k_mlp(
    const float* __restrict__ x, const float* __restrict__ eps,
    const float* __restrict__ mu_t, const float* __restrict__ lv_t,
    const float* __restrict__ b0, const float* __restrict__ bh,
    const float* __restrict__ Wo, const float* __restrict__ bo,
    const short* __restrict__ wf0, const short* __restrict__ wf1,
    const int* __restrict__ perm, const int* __restrict__ te,
    const int* __restrict__ tb, const int* __restrict__ tl,
    float* __restrict__ out)
{
  const int tid = threadIdx.x;
  const int w = tid >> 6, lane = tid & 63;
  const int hi = lane >> 5, col = lane & 31;
  const int bid = blockIdx.x;
  const int e = te[bid], base = tb[bid], lim = tl[bid];
  if(base >= lim) return;

  const int pos = base + w*32 + col;      // 32 samples per wave
  const bool valid = pos < lim;
  const int sid = perm[valid ? pos : (lim - 1)];
  const float bo_e = bo[e];

  // ---- layer-0 B-fragments (x_in^T): K = 80 (padded), 5 frags ----
  short8 bx[5];
  #pragma unroll
  for(int s=0;s<5;s++){
    short8 v;
    #pragma unroll
    for(int j=0;j<8;j++){
      int k = 16*s + 4*hi + (j & 3) + 8*(j >> 2);
      float f = 0.f;
      if(k < 3) f = x[sid*3 + k];
      else if(k < 67){
        int zi = k - 3;
        f = mu_t[e*64 + zi] + eps[(size_t)sid*64 + zi] * __expf(0.5f * lv_t[e*64 + zi]);
      }
      v[j] = f2bf(f);
    }
    bx[s] = v;
  }

  const short* w0e = wf0 + (size_t)e * (5*4096);
  const short* w1e = wf1 + (size_t)(0*8 + e) * (16*4096);
  const short* w2e = wf1 + (size_t)(1*8 + e) * (16*4096);

  f32x16 acc[8];
  #pragma unroll
  for(int t=0;t<8;t++)
    #pragma unroll
    for(int r=0;r<16;r++) acc[t][r] = 0.f;
  short8 hb[16];

  // ---- layer 0: 5 ksteps of K=16 ----
  #pragma unroll
  for(int ks=0; ks<5; ks++){
    const short* fb = w0e + ks*4096;
    #pragma unroll
    for(int t=0;t<8;t++){
      short8 a = *(const short8*)(fb + t*512 + lane*8);
      acc[t] = __builtin_amdgcn_mfma_f32_32x32x16_bf16(a, bx[ks], acc[t], 0, 0, 0);
    }
  }
  relu_repack32(acc, b0 + e*256, hi, hb);

  // ---- layer 1: 16 ksteps ----
  #pragma unroll
  for(int ks=0; ks<16; ks++){
    const short* fb = w1e + ks*4096;
    #pragma unroll
    for(int t=0;t<8;t++){
      short8 a = *(const short8*)(fb + t*512 + lane*8);
      acc[t] = __builtin_amdgcn_mfma_f32_32x32x16_bf16(a, hb[ks], acc[t], 0, 0, 0);
    }
  }
  relu_repack32(acc, bh + (0*8 + e)*256, hi, hb);

  // ---- layer 2: 16 ksteps ----
  #pragma unroll
  for(int ks=0; ks<16; ks++){
    const short* fb = w2e + ks*4096;
    #pragma unroll
    for(int t=0;t<8;t++){
      short8 a = *(const short8*)(fb + t*512 + lane*8);
      acc[t] = __builtin_amdgcn_mfma_f32_32x32x16_bf16(a, hb[ks], acc[t], 0, 0, 0);
    }
  }

  // ---- output layer ----
  float d = out_dot32(acc, bh + (1*8 + e)*256, Wo + e*256, hi);
  if(hi == 0 && valid) out[sid] = d + bo_e;
}

// ---------------- KL ----------------
__global__ void k_kl(const float* __restrict__ mu_t, const float* __restrict__ lv_t,
                     const unsigned* __restrict__ counts, float* __restrict__ klout){
  __shared__ float fe[8];
  int t = threadIdx.x;
  if(t < 8){
    float s = 0.f;
    for(int i=0;i<64;i++){
      float m = mu_t[t*64+i], l = lv_t[t*64+i];
      s += 1.f + l - m*m - expf(l);
    }
    fe[t] = s;
  }
  __syncthreads();
  if(t == 0){
    float kl = 0.f;
    for(int e=0;e<8;e++) kl += fe[e] * (float)counts[e];
    klout[0] = -0.5f * kl / (float)B_N;
  }
}

extern "C" void kernel_launch(void* const* d_in, const int* in_sizes, int n_in,
                              void* d_out, int out_size, void* d_ws, size_t ws_size,
                              hipStream_t stream){
  (void)in_sizes; (void)n_in; (void)out_size; (void)ws_size;
  const float* x   = (const float*)d_in[0];
  const int*   lab = (const int*)d_in[1];
  const float* eps = (const float*)d_in[2];
  const float* mu  = (const float*)d_in[3];
  const float* lv  = (const float*)d_in[4];
  const float* W0  = (const float*)d_in[5];
  const float* b0  = (const float*)d_in[6];
  const float* Wh  = (const float*)d_in[7];
  const float* bh  = (const float*)d_in[8];
  const float* Wo  = (const float*)d_in[9];
  const float* bo  = (const float*)d_in[10];
  float* out = (float*)d_out;

  char* ws = (char*)d_ws;
  unsigned* counts = (unsigned*)(ws + 0);
  unsigned* cursor = (unsigned*)(ws + 32);
  int* te   = (int*)(ws + 128);
  int* tb   = (int*)(ws + 128 + 4*MAXT);
  int* tl   = (int*)(ws + 128 + 8*MAXT);
  int* perm = (int*)(ws + 12544);
  short* wf0 = (short*)(ws + 274688);   // 8 e x 5 ks x 8 KB = 320 KB
  short* wf1 = (short*)(ws + 602368);   // 2 layers x 8 e x 16 ks x 8 KB = 2 MB

  hipMemsetAsync(ws, 0, 64, stream);  // counts + cursor
  k_hist<<<256, 256, 0, stream>>>(lab, counts);
  k_scan<<<1, 256, 0, stream>>>(counts, cursor, te, tb, tl);
  k_scatter<<<256, 256, 0, stream>>>(lab, cursor, perm);
  k_pw<<<(20480 + 131072 + 255)/256, 256, 0, stream>>>(W0, Wh, wf0, wf1);
  k_mlp<<<MAXT, 256, 0, stream>>>(x, eps, mu, lv, b0, bh, Wo, bo,
                                  wf0, wf1, perm, te, tb, tl, out);
  k_kl<<<1, 64, 0, stream>>>(mu, lv, counts, out + B_N);
}

// Round 4
// 99.145 us; speedup vs baseline: 1.5501x; 1.0894x over previous
//
#include <hip/hip_runtime.h>
#include <hip/hip_bf16.h>
#include <stdint.h>

#define B_N 65536
#define L_N 64
#define E_N 8
#define NS 128
#define MAXT (B_N/NS + E_N)   // 520 max tiles

typedef __attribute__((ext_vector_type(4))) float f32x4;
typedef __attribute__((ext_vector_type(16))) float f32x16;
typedef __attribute__((ext_vector_type(8))) short short8;

__device__ __forceinline__ short f2bf(float f){
  union { float f; unsigned u; } v; v.f = f;
  unsigned r = (v.u + 0x7fffu + ((v.u >> 16) & 1u)) >> 16;  // RNE
  return (short)r;
}

// ---------------- routing ----------------
__global__ void k_hist(const int* __restrict__ labels, unsigned* __restrict__ counts){
  __shared__ unsigned lc[8];
  if(threadIdx.x < 8) lc[threadIdx.x] = 0;
  __syncthreads();
  int i = blockIdx.x * blockDim.x + threadIdx.x;
  if(i < B_N) atomicAdd(&lc[labels[i] & 7], 1u);
  __syncthreads();
  if(threadIdx.x < 8 && lc[threadIdx.x]) atomicAdd(&counts[threadIdx.x], lc[threadIdx.x]);
}

__global__ void k_scan(const unsigned* __restrict__ counts, unsigned* __restrict__ cursor,
                       int* __restrict__ te, int* __restrict__ tb, int* __restrict__ tl){
  __shared__ int off[9], ts[9];
  if(threadIdx.x == 0){
    int o = 0, t = 0;
    for(int e=0;e<8;e++){
      off[e] = o; ts[e] = t;
      o += (int)counts[e];
      t += ((int)counts[e] + NS - 1) / NS;
    }
    off[8] = o; ts[8] = t;
    for(int e=0;e<8;e++) cursor[e] = (unsigned)off[e];
  }
  __syncthreads();
  for(int i = threadIdx.x; i < MAXT; i += blockDim.x){
    if(i < ts[8]){
      int e = 0;
      while(e < 7 && i >= ts[e+1]) e++;
      te[i] = e;
      tb[i] = off[e] + (i - ts[e]) * NS;
      tl[i] = off[e] + (int)counts[e];
    } else { te[i] = 0; tb[i] = 0; tl[i] = 0; }
  }
}

__global__ void k_scatter(const int* __restrict__ labels, unsigned* __restrict__ cursor,
                          int* __restrict__ perm){
  __shared__ unsigned lcnt[8], lbase[8];
  if(threadIdx.x < 8) lcnt[threadIdx.x] = 0;
  __syncthreads();
  int i = blockIdx.x * blockDim.x + threadIdx.x;
  int e = 0; unsigned r = 0;
  if(i < B_N){ e = labels[i] & 7; r = atomicAdd(&lcnt[e], 1u); }
  __syncthreads();
  if(threadIdx.x < 8 && lcnt[threadIdx.x])
    lbase[threadIdx.x] = atomicAdd(&cursor[threadIdx.x], lcnt[threadIdx.x]);
  __syncthreads();
  if(i < B_N) perm[lbase[e] + r] = i;
}

// ---------------- weight fragment prep (32x32x16 A-frags) ----------------
// per (expert, kstep16): [t 0..7][lane 0..63][j 0..7] bf16 (16B/lane)
// A elem (lane l, j): m = 32t + (l&31); k = 16s + 4*(l>>5) + (j&3) + 8*(j>>2)
__global__ void k_pw(const float* __restrict__ W0, const float* __restrict__ Wh,
                     short* __restrict__ wf0, short* __restrict__ wf1){
  int uid = blockIdx.x * blockDim.x + threadIdx.x;
  const int NU0 = 8*5*8*64;        // 20480 (layer0: K=67 -> 5 ksteps of 16)
  const int NU1 = 2*8*16*8*64;     // 131072 (hidden: K=256 -> 16 ksteps)
  if(uid < NU0){
    int e = uid / 2560, r = uid % 2560;
    int s = r / 512, r2 = r % 512, t = r2 / 64, l = r2 % 64;
    int hi = l >> 5, m = 32*t + (l & 31);
    short8 v;
    #pragma unroll
    for(int j=0;j<8;j++){
      int k = 16*s + 4*hi + (j & 3) + 8*(j >> 2);
      float f = (k < 67) ? W0[(e*67 + k)*256 + m] : 0.f;
      v[j] = f2bf(f);
    }
    *(short8*)(wf0 + (size_t)uid * 8) = v;
  } else if(uid < NU0 + NU1){
    int u = uid - NU0;
    int le = u / 8192, r1 = u % 8192;           // le = lh*8 + e
    int s = r1 / 512, r2 = r1 % 512, t = r2 / 64, l = r2 % 64;
    int hi = l >> 5, m = 32*t + (l & 31);
    short8 v;
    #pragma unroll
    for(int j=0;j<8;j++){
      int k = 16*s + 4*hi + (j & 3) + 8*(j >> 2);
      v[j] = f2bf(Wh[((size_t)le*256 + k)*256 + m]);
    }
    *(short8*)(wf1 + (size_t)u * 8) = v;
  }
}

// ---------------- fused MoE MLP (barrier-free, 32x32x16, hb in wave-private LDS) ----------------
__global__ __launch_bounds__(256, 2) void k_mlp(
    const float* __restrict__ x, const float* __restrict__ eps,
    const float* __restrict__ mu_t, const float* __restrict__ lv_t,
    const float* __restrict__ b0, const float* __restrict__ bh,
    const float* __restrict__ Wo, const float* __restrict__ bo,
    const short* __restrict__ wf0, const short* __restrict__ wf1,
    const int* __restrict__ perm, const int* __restrict__ te,
    const int* __restrict__ tb, const int* __restrict__ tl,
    float* __restrict__ out)
{
  __shared__ short bfrag[4][16][64][8];   // 64 KB: per-wave B-fragment store

  const int tid = threadIdx.x;
  const int w = tid >> 6, lane = tid & 63;
  const int hi = lane >> 5, col = lane & 31;
  const int bid = blockIdx.x;
  const int e = te[bid], base = tb[bid], lim = tl[bid];
  if(base >= lim) return;

  const int pos = base + w*32 + col;      // 32 samples per wave
  const bool valid = pos < lim;
  const int sid = perm[valid ? pos : (lim - 1)];
  const float bo_e = bo[e];

  short* myfrag = &bfrag[w][0][lane][0];  // frag s at offset s*512 shorts

  // ---- layer-0 B-fragments (x_in^T): K = 80 (padded), kept in registers ----
  short8 bx[5];
  #pragma unroll
  for(int s=0;s<5;s++){
    short8 v;
    #pragma unroll
    for(int j=0;j<8;j++){
      int k = 16*s + 4*hi + (j & 3) + 8*(j >> 2);
      float f = 0.f;
      if(k < 3) f = x[sid*3 + k];
      else if(k < 67){
        int zi = k - 3;
        f = mu_t[e*64 + zi] + eps[(size_t)sid*64 + zi] * __expf(0.5f * lv_t[e*64 + zi]);
      }
      v[j] = f2bf(f);
    }
    bx[s] = v;
  }

  const short* w0e = wf0 + (size_t)e * (5*4096);
  const short* w1e = wf1 + (size_t)(0*8 + e) * (16*4096);
  const short* w2e = wf1 + (size_t)(1*8 + e) * (16*4096);

  f32x16 acc[8];
  #pragma unroll
  for(int t=0;t<8;t++)
    #pragma unroll
    for(int r=0;r<16;r++) acc[t][r] = 0.f;

  // ---- layer 0: 5 ksteps of K=16 (B from registers) ----
  #pragma unroll
  for(int ks=0; ks<5; ks++){
    const short* fb = w0e + ks*4096;
    #pragma unroll
    for(int t=0;t<8;t++){
      short8 a = *(const short8*)(fb + t*512 + lane*8);
      acc[t] = __builtin_amdgcn_mfma_f32_32x32x16_bf16(a, bx[ks], acc[t], 0, 0, 0);
    }
  }

  // epilogue 0: bias+relu, repack into LDS B-frags
  {
    const float* bias = b0 + e*256;
    #pragma unroll
    for(int t=0;t<8;t++){
      #pragma unroll
      for(int q=0;q<4;q++){
        f32x4 b4 = *(const f32x4*)(bias + 32*t + 4*hi + 8*q);
        #pragma unroll
        for(int r=0;r<4;r++){
          float vv = acc[t][4*q+r] + b4[r];
          acc[t][4*q+r] = vv > 0.f ? vv : 0.f;
        }
      }
      short8 h0, h1;
      #pragma unroll
      for(int j=0;j<8;j++){ h0[j] = f2bf(acc[t][j]); h1[j] = f2bf(acc[t][8+j]); }
      *(short8*)(myfrag + (2*t)*512) = h0;
      *(short8*)(myfrag + (2*t+1)*512) = h1;
      #pragma unroll
      for(int r=0;r<16;r++) acc[t][r] = 0.f;
    }
  }

  // ---- layer 1: 16 ksteps (B from LDS, bounded unroll) ----
  #pragma unroll 2
  for(int ks=0; ks<16; ks++){
    short8 b = *(const short8*)(myfrag + ks*512);
    const short* fb = w1e + ks*4096;
    #pragma unroll
    for(int t=0;t<8;t++){
      short8 a = *(const short8*)(fb + t*512 + lane*8);
      acc[t] = __builtin_amdgcn_mfma_f32_32x32x16_bf16(a, b, acc[t], 0, 0, 0);
    }
  }

  // epilogue 1
  {
    const float* bias = bh + (0*8 + e)*256;
    #pragma unroll
    for(int t=0;t<8;t++){
      #pragma unroll
      for(int q=0;q<4;q++){
        f32x4 b4 = *(const f32x4*)(bias + 32*t + 4*hi + 8*q);
        #pragma unroll
        for(int r=0;r<4;r++){
          float vv = acc[t][4*q+r] + b4[r];
          acc[t][4*q+r] = vv > 0.f ? vv : 0.f;
        }
      }
      short8 h0, h1;
      #pragma unroll
      for(int j=0;j<8;j++){ h0[j] = f2bf(acc[t][j]); h1[j] = f2bf(acc[t][8+j]); }
      *(short8*)(myfrag + (2*t)*512) = h0;
      *(short8*)(myfrag + (2*t+1)*512) = h1;
      #pragma unroll
      for(int r=0;r<16;r++) acc[t][r] = 0.f;
    }
  }

  // ---- layer 2: 16 ksteps ----
  #pragma unroll 2
  for(int ks=0; ks<16; ks++){
    short8 b = *(const short8*)(myfrag + ks*512);
    const short* fb = w2e + ks*4096;
    #pragma unroll
    for(int t=0;t<8;t++){
      short8 a = *(const short8*)(fb + t*512 + lane*8);
      acc[t] = __builtin_amdgcn_mfma_f32_32x32x16_bf16(a, b, acc[t], 0, 0, 0);
    }
  }

  // ---- output layer: bias+relu then dot with Wo, reduce across hi halves ----
  float dot = 0.f;
  {
    const float* bias = bh + (1*8 + e)*256;
    const float* wo = Wo + e*256;
    #pragma unroll
    for(int t=0;t<8;t++){
      #pragma unroll
      for(int q=0;q<4;q++){
        f32x4 b4 = *(const f32x4*)(bias + 32*t + 4*hi + 8*q);
        f32x4 w4 = *(const f32x4*)(wo + 32*t + 4*hi + 8*q);
        #pragma unroll
        for(int r=0;r<4;r++){
          float vv = acc[t][4*q+r] + b4[r];
          vv = vv > 0.f ? vv : 0.f;
          dot += vv * w4[r];
        }
      }
    }
  }
  dot += __shfl_xor(dot, 32, 64);
  if(hi == 0 && valid) out[sid] = dot + bo_e;
}

// ---------------- KL ----------------
__global__ void k_kl(const float* __restrict__ mu_t, const float* __restrict__ lv_t,
                     const unsigned* __restrict__ counts, float* __restrict__ klout){
  __shared__ float fe[8];
  int t = threadIdx.x;
  if(t < 8){
    float s = 0.f;
    for(int i=0;i<64;i++){
      float m = mu_t[t*64+i], l = lv_t[t*64+i];
      s += 1.f + l - m*m - expf(l);
    }
    fe[t] = s;
  }
  __syncthreads();
  if(t == 0){
    float kl = 0.f;
    for(int e=0;e<8;e++) kl += fe[e] * (float)counts[e];
    klout[0] = -0.5f * kl / (float)B_N;
  }
}

extern "C" void kernel_launch(void* const* d_in, const int* in_sizes, int n_in,
                              void* d_out, int out_size, void* d_ws, size_t ws_size,
                              hipStream_t stream){
  (void)in_sizes; (void)n_in; (void)out_size; (void)ws_size;
  const float* x   = (const float*)d_in[0];
  const int*   lab = (const int*)d_in[1];
  const float* eps = (const float*)d_in[2];
  const float* mu  = (const float*)d_in[3];
  const float* lv  = (const float*)d_in[4];
  const float* W0  = (const float*)d_in[5];
  const float* b0  = (const float*)d_in[6];
  const float* Wh  = (const float*)d_in[7];
  const float* bh  = (const float*)d_in[8];
  const float* Wo  = (const float*)d_in[9];
  const float* bo  = (const float*)d_in[10];
  float* out = (float*)d_out;

  char* ws = (char*)d_ws;
  unsigned* counts = (unsigned*)(ws + 0);
  unsigned* cursor = (unsigned*)(ws + 32);
  int* te   = (int*)(ws + 128);
  int* tb   = (int*)(ws + 128 + 4*MAXT);
  int* tl   = (int*)(ws + 128 + 8*MAXT);
  int* perm = (int*)(ws + 12544);
  short* wf0 = (short*)(ws + 274688);   // 8 e x 5 ks x 8 KB = 320 KB
  short* wf1 = (short*)(ws + 602368);   // 2 layers x 8 e x 16 ks x 8 KB = 2 MB

  hipMemsetAsync(ws, 0, 64, stream);  // counts + cursor
  k_hist<<<256, 256, 0, stream>>>(lab, counts);
  k_scan<<<1, 256, 0, stream>>>(counts, cursor, te, tb, tl);
  k_scatter<<<256, 256, 0, stream>>>(lab, cursor, perm);
  k_pw<<<(20480 + 131072 + 255)/256, 256, 0, stream>>>(W0, Wh, wf0, wf1);
  k_mlp<<<MAXT, 256, 0, stream>>>(x, eps, mu, lv, b0, bh, Wo, bo,
                                  wf0, wf1, perm, te, tb, tl, out);
  k_kl<<<1, 64, 0, stream>>>(mu, lv, counts, out + B_N);
}

// Round 5
// 95.354 us; speedup vs baseline: 1.6117x; 1.0398x over previous
//
#include <hip/hip_runtime.h>
#include <hip/hip_bf16.h>
#include <stdint.h>

#define B_N 65536
#define L_N 64
#define E_N 8
#define NS 128
#define MAXT (B_N/NS + E_N)   // 520 max tiles

typedef __attribute__((ext_vector_type(4))) float f32x4;
typedef __attribute__((ext_vector_type(16))) float f32x16;
typedef __attribute__((ext_vector_type(8))) short short8;

__device__ __forceinline__ short f2bf(float f){
  union { float f; unsigned u; } v; v.f = f;
  unsigned r = (v.u + 0x7fffu + ((v.u >> 16) & 1u)) >> 16;  // RNE
  return (short)r;
}

// ---------------- routing ----------------
__global__ void k_hist(const int* __restrict__ labels, unsigned* __restrict__ counts){
  __shared__ unsigned lc[8];
  if(threadIdx.x < 8) lc[threadIdx.x] = 0;
  __syncthreads();
  int i = blockIdx.x * blockDim.x + threadIdx.x;
  if(i < B_N) atomicAdd(&lc[labels[i] & 7], 1u);
  __syncthreads();
  if(threadIdx.x < 8 && lc[threadIdx.x]) atomicAdd(&counts[threadIdx.x], lc[threadIdx.x]);
}

__global__ void k_scan(const unsigned* __restrict__ counts, unsigned* __restrict__ cursor,
                       int* __restrict__ te, int* __restrict__ tb, int* __restrict__ tl){
  __shared__ int off[9], ts[9];
  if(threadIdx.x == 0){
    int o = 0, t = 0;
    for(int e=0;e<8;e++){
      off[e] = o; ts[e] = t;
      o += (int)counts[e];
      t += ((int)counts[e] + NS - 1) / NS;
    }
    off[8] = o; ts[8] = t;
    for(int e=0;e<8;e++) cursor[e] = (unsigned)off[e];
  }
  __syncthreads();
  for(int i = threadIdx.x; i < MAXT; i += blockDim.x){
    if(i < ts[8]){
      int e = 0;
      while(e < 7 && i >= ts[e+1]) e++;
      te[i] = e;
      tb[i] = off[e] + (i - ts[e]) * NS;
      tl[i] = off[e] + (int)counts[e];
    } else { te[i] = 0; tb[i] = 0; tl[i] = 0; }
  }
}

__global__ void k_scatter(const int* __restrict__ labels, unsigned* __restrict__ cursor,
                          int* __restrict__ perm){
  __shared__ unsigned lcnt[8], lbase[8];
  if(threadIdx.x < 8) lcnt[threadIdx.x] = 0;
  __syncthreads();
  int i = blockIdx.x * blockDim.x + threadIdx.x;
  int e = 0; unsigned r = 0;
  if(i < B_N){ e = labels[i] & 7; r = atomicAdd(&lcnt[e], 1u); }
  __syncthreads();
  if(threadIdx.x < 8 && lcnt[threadIdx.x])
    lbase[threadIdx.x] = atomicAdd(&cursor[threadIdx.x], lcnt[threadIdx.x]);
  __syncthreads();
  if(i < B_N) perm[lbase[e] + r] = i;
}

// ---------------- weight fragment prep (32x32x16 A-frags) ----------------
// per (expert, kstep16): [t 0..7][lane 0..63][j 0..7] bf16 (16B/lane)
// A elem (lane l, j): m = 32t + (l&31); k = 16s + 4*(l>>5) + (j&3) + 8*(j>>2)
__global__ void k_pw(const float* __restrict__ W0, const float* __restrict__ Wh,
                     short* __restrict__ wf0, short* __restrict__ wf1){
  int uid = blockIdx.x * blockDim.x + threadIdx.x;
  const int NU0 = 8*5*8*64;        // 20480 (layer0: K=67 -> 5 ksteps of 16)
  const int NU1 = 2*8*16*8*64;     // 131072 (hidden: K=256 -> 16 ksteps)
  if(uid < NU0){
    int e = uid / 2560, r = uid % 2560;
    int s = r / 512, r2 = r % 512, t = r2 / 64, l = r2 % 64;
    int hi = l >> 5, m = 32*t + (l & 31);
    short8 v;
    #pragma unroll
    for(int j=0;j<8;j++){
      int k = 16*s + 4*hi + (j & 3) + 8*(j >> 2);
      float f = (k < 67) ? W0[(e*67 + k)*256 + m] : 0.f;
      v[j] = f2bf(f);
    }
    *(short8*)(wf0 + (size_t)uid * 8) = v;
  } else if(uid < NU0 + NU1){
    int u = uid - NU0;
    int le = u / 8192, r1 = u % 8192;           // le = lh*8 + e
    int s = r1 / 512, r2 = r1 % 512, t = r2 / 64, l = r2 % 64;
    int hi = l >> 5, m = 32*t + (l & 31);
    short8 v;
    #pragma unroll
    for(int j=0;j<8;j++){
      int k = 16*s + 4*hi + (j & 3) + 8*(j >> 2);
      v[j] = f2bf(Wh[((size_t)le*256 + k)*256 + m]);
    }
    *(short8*)(wf1 + (size_t)u * 8) = v;
  }
}

// ---------------- fused MoE MLP: LDS-staged A-tiles, counted vmcnt, raw barriers ------------
// 8 waves = 4 pairs; pair p owns 32 samples; roles split the 8 feature-tiles (4 each).
__global__ __launch_bounds__(512, 2) void k_mlp(
    const float* __restrict__ x, const float* __restrict__ eps,
    const float* __restrict__ mu_t, const float* __restrict__ lv_t,
    const float* __restrict__ b0, const float* __restrict__ bh,
    const float* __restrict__ Wo, const float* __restrict__ bo,
    const short* __restrict__ wf0, const short* __restrict__ wf1,
    const int* __restrict__ perm, const int* __restrict__ te,
    const int* __restrict__ tb, const int* __restrict__ tl,
    float* __restrict__ out)
{
  __shared__ __align__(16) short abuf[3][8][64][8];    // 24 KB triple-buffered A-tile
  __shared__ __align__(16) short bfrag[4][16][64][8];  // 64 KB pair-shared B-frags
  __shared__ __align__(16) float bias_lds[3][256];
  __shared__ __align__(16) float wo_lds[256];
  __shared__ __align__(16) float odot[4][2][32];

  const int tid  = threadIdx.x;
  const int w    = tid >> 6, lane = tid & 63;
  const int hi   = lane >> 5, col = lane & 31;
  const int p    = w >> 1, role = w & 1;
  const int bid  = blockIdx.x;
  const int e = te[bid], base = tb[bid], lim = tl[bid];
  if(base >= lim) return;

  // stage biases + Wo into LDS (drained by lgkmcnt before first barrier)
  if(tid < 256){
    bias_lds[0][tid] = b0[e*256 + tid];
    bias_lds[2][tid] = bh[(8 + e)*256 + tid];
  } else {
    int t2 = tid - 256;
    bias_lds[1][t2] = bh[(0*8 + e)*256 + t2];
    wo_lds[t2]      = Wo[e*256 + t2];
  }

  const int pos = base + p*32 + col;      // both waves of a pair: same 32 samples
  const bool valid = pos < lim;
  const int sid = perm[valid ? pos : (lim - 1)];
  const float bo_e = bo[e];

  // ---- layer-0 B-fragments (x_in^T), K = 80 padded, in registers ----
  short8 bx[5];
  #pragma unroll
  for(int s=0;s<5;s++){
    short8 v;
    #pragma unroll
    for(int j=0;j<8;j++){
      int k = 16*s + 4*hi + (j & 3) + 8*(j >> 2);
      float f = 0.f;
      if(k < 3) f = x[sid*3 + k];
      else if(k < 67){
        int zi = k - 3;
        f = mu_t[e*64 + zi] + eps[(size_t)sid*64 + zi] * __expf(0.5f * lv_t[e*64 + zi]);
      }
      v[j] = f2bf(f);
    }
    bx[s] = v;
  }

  const short* w0e = wf0 + (size_t)e * (5*4096);
  const short* w1e = wf1 + (size_t)(0*8 + e) * (16*4096);
  const short* w2e = wf1 + (size_t)(1*8 + e) * (16*4096);

  short* myfrag = (short*)&bfrag[p][0][0][0] + lane*8;   // frag f at +f*512

  f32x16 acc[4];
  #pragma unroll
  for(int t=0;t<4;t++)
    #pragma unroll
    for(int r=0;r<16;r++) acc[t][r] = 0.f;

  // stage: thread tid copies 16B chunk tid of kstep tile ks into abuf[ks%3]
  auto srcof = [&](int ks)->const short*{
    return (ks < 5) ? (w0e + ks*4096) : (ks < 21) ? (w1e + (ks-5)*4096) : (w2e + (ks-21)*4096);
  };
  auto stage = [&](int ks){
    const short* gp = srcof(ks) + tid*8;
    short* lp = (short*)&abuf[ks%3][0][0][0] + w*512;    // wave-uniform base; HW adds lane*16B
    __builtin_amdgcn_global_load_lds((const __attribute__((address_space(1))) void*)gp,
                                     (__attribute__((address_space(3))) void*)lp, 16, 0, 0);
  };

  #define KSTEP_SYNC(last)                                                        \
    if(last) { asm volatile("s_waitcnt vmcnt(0) lgkmcnt(0)" ::: "memory"); }      \
    else     { asm volatile("s_waitcnt vmcnt(1) lgkmcnt(0)" ::: "memory"); }      \
    __builtin_amdgcn_s_barrier();                                                 \
    __builtin_amdgcn_sched_barrier(0);

  auto compute = [&](int ks, short8 b){
    const short* ab = (const short*)&abuf[ks%3][0][0][0];
    #pragma unroll
    for(int t=0;t<4;t++){
      int tg = role*4 + t;
      short8 a = *(const short8*)(ab + tg*512 + lane*8);
      acc[t] = __builtin_amdgcn_mfma_f32_32x32x16_bf16(a, b, acc[t], 0, 0, 0);
    }
  };

  auto epilogue = [&](const float* bias_row){
    #pragma unroll
    for(int t=0;t<4;t++){
      int tg = role*4 + t;
      #pragma unroll
      for(int q=0;q<4;q++){
        f32x4 b4 = *(const f32x4*)(bias_row + 32*tg + 4*hi + 8*q);
        #pragma unroll
        for(int r=0;r<4;r++){
          float vv = acc[t][4*q+r] + b4[r];
          acc[t][4*q+r] = vv > 0.f ? vv : 0.f;
        }
      }
      short8 h0, h1;
      #pragma unroll
      for(int j=0;j<8;j++){ h0[j] = f2bf(acc[t][j]); h1[j] = f2bf(acc[t][8+j]); }
      *(short8*)(myfrag + (2*tg)*512) = h0;
      *(short8*)(myfrag + (2*tg+1)*512) = h1;
      #pragma unroll
      for(int r=0;r<16;r++) acc[t][r] = 0.f;
    }
  };

  // prologue: fill pipeline 2 deep
  stage(0); stage(1);

  // ---- layer 0: ks 0..4 (B from registers, static index) ----
  #pragma unroll
  for(int ks=0; ks<5; ks++){
    KSTEP_SYNC(false)
    stage(ks+2);
    compute(ks, bx[ks]);
  }
  epilogue(&bias_lds[0][0]);   // writes own frags; layer-0 reads used bx only -> no race

  // ---- layer 1: ks 5..20 (B from pair-shared LDS) ----
  #pragma unroll 2
  for(int i=0; i<16; i++){
    int ks = 5 + i;
    KSTEP_SYNC(false)
    stage(ks+2);
    short8 b = *(const short8*)(myfrag + i*512);
    compute(ks, b);
  }
  // close cross-wave race: partner may still be reading bfrag for ks=20
  asm volatile("s_waitcnt lgkmcnt(0)" ::: "memory");
  __builtin_amdgcn_s_barrier();
  epilogue(&bias_lds[1][0]);

  // ---- layer 2: ks 21..36 ----
  #pragma unroll 2
  for(int i=0; i<16; i++){
    int ks = 21 + i;
    KSTEP_SYNC(ks == 36)
    if(ks + 2 < 37) stage(ks+2);
    short8 b = *(const short8*)(myfrag + i*512);
    compute(ks, b);
  }

  // ---- output layer: bias+relu, dot with Wo, reduce hi halves then roles ----
  float dot = 0.f;
  #pragma unroll
  for(int t=0;t<4;t++){
    int tg = role*4 + t;
    #pragma unroll
    for(int q=0;q<4;q++){
      f32x4 b4 = *(const f32x4*)(&bias_lds[2][32*tg + 4*hi + 8*q]);
      f32x4 w4 = *(const f32x4*)(&wo_lds[32*tg + 4*hi + 8*q]);
      #pragma unroll
      for(int r=0;r<4;r++){
        float vv = acc[t][4*q+r] + b4[r];
        vv = vv > 0.f ? vv : 0.f;
        dot += vv * w4[r];
      }
    }
  }
  dot += __shfl_xor(dot, 32, 64);
  if(hi == 0) odot[p][role][col] = dot;
  asm volatile("s_waitcnt lgkmcnt(0)" ::: "memory");
  __builtin_amdgcn_s_barrier();
  if(role == 0 && hi == 0 && valid)
    out[sid] = odot[p][0][col] + odot[p][1][col] + bo_e;
  #undef KSTEP_SYNC
}

// ---------------- KL ----------------
__global__ void k_kl(const float* __restrict__ mu_t, const float* __restrict__ lv_t,
                     const unsigned* __restrict__ counts, float* __restrict__ klout){
  __shared__ float fe[8];
  int t = threadIdx.x;
  if(t < 8){
    float s = 0.f;
    for(int i=0;i<64;i++){
      float m = mu_t[t*64+i], l = lv_t[t*64+i];
      s += 1.f + l - m*m - expf(l);
    }
    fe[t] = s;
  }
  __syncthreads();
  if(t == 0){
    float kl = 0.f;
    for(int e=0;e<8;e++) kl += fe[e] * (float)counts[e];
    klout[0] = -0.5f * kl / (float)B_N;
  }
}

extern "C" void kernel_launch(void* const* d_in, const int* in_sizes, int n_in,
                              void* d_out, int out_size, void* d_ws, size_t ws_size,
                              hipStream_t stream){
  (void)in_sizes; (void)n_in; (void)out_size; (void)ws_size;
  const float* x   = (const float*)d_in[0];
  const int*   lab = (const int*)d_in[1];
  const float* eps = (const float*)d_in[2];
  const float* mu  = (const float*)d_in[3];
  const float* lv  = (const float*)d_in[4];
  const float* W0  = (const float*)d_in[5];
  const float* b0  = (const float*)d_in[6];
  const float* Wh  = (const float*)d_in[7];
  const float* bh  = (const float*)d_in[8];
  const float* Wo  = (const float*)d_in[9];
  const float* bo  = (const float*)d_in[10];
  float* out = (float*)d_out;

  char* ws = (char*)d_ws;
  unsigned* counts = (unsigned*)(ws + 0);
  unsigned* cursor = (unsigned*)(ws + 32);
  int* te   = (int*)(ws + 128);
  int* tb   = (int*)(ws + 128 + 4*MAXT);
  int* tl   = (int*)(ws + 128 + 8*MAXT);
  int* perm = (int*)(ws + 12544);
  short* wf0 = (short*)(ws + 274688);   // 8 e x 5 ks x 8 KB = 320 KB
  short* wf1 = (short*)(ws + 602368);   // 2 layers x 8 e x 16 ks x 8 KB = 2 MB

  hipMemsetAsync(ws, 0, 64, stream);  // counts + cursor
  k_hist<<<256, 256, 0, stream>>>(lab, counts);
  k_scan<<<1, 256, 0, stream>>>(counts, cursor, te, tb, tl);
  k_scatter<<<256, 256, 0, stream>>>(lab, cursor, perm);
  k_pw<<<(20480 + 131072 + 255)/256, 256, 0, stream>>>(W0, Wh, wf0, wf1);
  k_mlp<<<MAXT, 512, 0, stream>>>(x, eps, mu, lv, b0, bh, Wo, bo,
                                  wf0, wf1, perm, te, tb, tl, out);
  k_kl<<<1, 64, 0, stream>>>(mu, lv, counts, out + B_N);
}

// Round 6
// 80.444 us; speedup vs baseline: 1.9105x; 1.1853x over previous
//
#include <hip/hip_runtime.h>
#include <hip/hip_bf16.h>
#include <stdint.h>

#define B_N 65536
#define L_N 64
#define E_N 8
#define SPB 256
#define MAXT (B_N/SPB + E_N)   // 264 max tiles

typedef __attribute__((ext_vector_type(4))) float f32x4;
typedef __attribute__((ext_vector_type(16))) float f32x16;
typedef __attribute__((ext_vector_type(8))) short short8;

__device__ __forceinline__ short f2bf(float f){
  union { float f; unsigned u; } v; v.f = f;
  unsigned r = (v.u + 0x7fffu + ((v.u >> 16) & 1u)) >> 16;  // RNE
  return (short)r;
}

// ---------------- routing ----------------
__global__ void k_hist(const int* __restrict__ labels, unsigned* __restrict__ counts){
  __shared__ unsigned lc[8];
  if(threadIdx.x < 8) lc[threadIdx.x] = 0;
  __syncthreads();
  int i = blockIdx.x * blockDim.x + threadIdx.x;
  if(i < B_N) atomicAdd(&lc[labels[i] & 7], 1u);
  __syncthreads();
  if(threadIdx.x < 8 && lc[threadIdx.x]) atomicAdd(&counts[threadIdx.x], lc[threadIdx.x]);
}

__global__ void k_scan(const unsigned* __restrict__ counts, unsigned* __restrict__ cursor,
                       int* __restrict__ te, int* __restrict__ tb, int* __restrict__ tl){
  __shared__ int off[9], ts[9];
  if(threadIdx.x == 0){
    int o = 0, t = 0;
    for(int e=0;e<8;e++){
      off[e] = o; ts[e] = t;
      o += (int)counts[e];
      t += ((int)counts[e] + SPB - 1) / SPB;
    }
    off[8] = o; ts[8] = t;
    for(int e=0;e<8;e++) cursor[e] = (unsigned)off[e];
  }
  __syncthreads();
  for(int i = threadIdx.x; i < MAXT; i += blockDim.x){
    if(i < ts[8]){
      int e = 0;
      while(e < 7 && i >= ts[e+1]) e++;
      te[i] = e;
      tb[i] = off[e] + (i - ts[e]) * SPB;
      tl[i] = off[e] + (int)counts[e];
    } else { te[i] = 0; tb[i] = 0; tl[i] = 0; }
  }
}

__global__ void k_scatter(const int* __restrict__ labels, unsigned* __restrict__ cursor,
                          int* __restrict__ perm){
  __shared__ unsigned lcnt[8], lbase[8];
  if(threadIdx.x < 8) lcnt[threadIdx.x] = 0;
  __syncthreads();
  int i = blockIdx.x * blockDim.x + threadIdx.x;
  int e = 0; unsigned r = 0;
  if(i < B_N){ e = labels[i] & 7; r = atomicAdd(&lcnt[e], 1u); }
  __syncthreads();
  if(threadIdx.x < 8 && lcnt[threadIdx.x])
    lbase[threadIdx.x] = atomicAdd(&cursor[threadIdx.x], lcnt[threadIdx.x]);
  __syncthreads();
  if(i < B_N) perm[lbase[e] + r] = i;
}

// ---------------- weight fragment prep (32x32x16 A-frags) ----------------
// per (expert, kstep16): [t 0..7][lane 0..63][j 0..7] bf16 (16B/lane)
// A elem (lane l, j): m = 32t + (l&31); k = 16s + 4*(l>>5) + (j&3) + 8*(j>>2)
// layer 0 padded to 6 ksteps (K=96), zeros beyond k=66
__global__ void k_pw(const float* __restrict__ W0, const float* __restrict__ Wh,
                     short* __restrict__ wf0, short* __restrict__ wf1){
  int uid = blockIdx.x * blockDim.x + threadIdx.x;
  const int NU0 = 8*6*8*64;        // 24576
  const int NU1 = 2*8*16*8*64;     // 131072
  if(uid < NU0){
    int e = uid / 3072, r = uid % 3072;
    int s = r / 512, r2 = r % 512, t = r2 / 64, l = r2 % 64;
    int hi = l >> 5, m = 32*t + (l & 31);
    short8 v;
    #pragma unroll
    for(int j=0;j<8;j++){
      int k = 16*s + 4*hi + (j & 3) + 8*(j >> 2);
      float f = (k < 67) ? W0[(e*67 + k)*256 + m] : 0.f;
      v[j] = f2bf(f);
    }
    *(short8*)(wf0 + (size_t)uid * 8) = v;
  } else if(uid < NU0 + NU1){
    int u = uid - NU0;
    int le = u / 8192, r1 = u % 8192;           // le = lh*8 + e
    int s = r1 / 512, r2 = r1 % 512, t = r2 / 64, l = r2 % 64;
    int hi = l >> 5, m = 32*t + (l & 31);
    short8 v;
    #pragma unroll
    for(int j=0;j<8;j++){
      int k = 16*s + 4*hi + (j & 3) + 8*(j >> 2);
      v[j] = f2bf(Wh[((size_t)le*256 + k)*256 + m]);
    }
    *(short8*)(wf1 + (size_t)u * 8) = v;
  }
}

// ---------------- fused MoE MLP: 256 samples/block, 19 sync-walls, counted vmcnt ----------
__global__ __launch_bounds__(512, 2) void k_mlp(
    const float* __restrict__ x, const float* __restrict__ eps,
    const float* __restrict__ mu_t, const float* __restrict__ lv_t,
    const float* __restrict__ b0, const float* __restrict__ bh,
    const float* __restrict__ Wo, const float* __restrict__ bo,
    const short* __restrict__ wf0, const short* __restrict__ wf1,
    const int* __restrict__ perm, const int* __restrict__ te,
    const int* __restrict__ tb, const int* __restrict__ tl,
    float* __restrict__ out)
{
  __shared__ __align__(16) short abuf[3][8192];   // 3 x 16KB A-tile (2 ksteps each)
  __shared__ __align__(16) float bias_lds[3][256];
  __shared__ __align__(16) float wo_lds[256];

  const int tid  = threadIdx.x;
  const int w    = tid >> 6, lane = tid & 63;
  const int hi   = lane >> 5, col = lane & 31;
  const int bid  = blockIdx.x;
  const int e = te[bid], base = tb[bid], lim = tl[bid];
  if(base >= lim) return;

  if(tid < 256){
    bias_lds[0][tid] = b0[e*256 + tid];
    bias_lds[2][tid] = bh[(8 + e)*256 + tid];
  } else {
    int t2 = tid - 256;
    bias_lds[1][t2] = bh[e*256 + t2];
    wo_lds[t2]      = Wo[e*256 + t2];
  }

  const int pos = base + w*32 + col;      // each wave owns 32 samples
  const bool valid = pos < lim;
  const int sid = perm[valid ? pos : (lim - 1)];
  const float bo_e = bo[e];

  // ---- layer-0 B-fragments (x_in^T), K=96 padded, into hb[0..5] ----
  short8 hb[16];
  #pragma unroll
  for(int s=0;s<6;s++){
    short8 v;
    #pragma unroll
    for(int j=0;j<8;j++){
      int k = 16*s + 4*hi + (j & 3) + 8*(j >> 2);
      float f = 0.f;
      if(k < 3) f = x[sid*3 + k];
      else if(k < 67){
        int zi = k - 3;
        f = mu_t[e*64 + zi] + eps[(size_t)sid*64 + zi] * __expf(0.5f * lv_t[e*64 + zi]);
      }
      v[j] = f2bf(f);
    }
    hb[s] = v;
  }
  #pragma unroll
  for(int s=6;s<16;s++) hb[s] = short8{0,0,0,0,0,0,0,0};

  const short* w0e = wf0 + (size_t)e * (6*4096);
  const short* w1e = wf1 + (size_t)(0*8 + e) * (16*4096);
  const short* w2e = wf1 + (size_t)(1*8 + e) * (16*4096);

  f32x16 acc[8];
  #pragma unroll
  for(int t=0;t<8;t++)
    #pragma unroll
    for(int r=0;r<16;r++) acc[t][r] = 0.f;

  // stage one 16KB tile (2 ksteps): 2 x global_load_lds(16B) per thread
  auto stage2 = [&](const short* srcT, int bufidx){
    #pragma unroll
    for(int c=0;c<2;c++){
      const char* gp = (const char*)srcT + tid*16 + c*8192;
      char* lp = (char*)&abuf[bufidx][0] + c*8192 + w*1024;  // wave-uniform; HW adds lane*16B
      __builtin_amdgcn_global_load_lds((const __attribute__((address_space(1))) void*)gp,
                                       (__attribute__((address_space(3))) void*)lp, 16, 0, 0);
    }
  };

  // compute one tile: 2 ksteps x 8 feature-tiles
  auto compute2 = [&](int bufidx, short8 bf0, short8 bf1){
    const char* ab = (const char*)&abuf[bufidx][0];
    #pragma unroll
    for(int t=0;t<8;t++){
      short8 a = *(const short8*)(ab + t*1024 + lane*16);
      acc[t] = __builtin_amdgcn_mfma_f32_32x32x16_bf16(a, bf0, acc[t], 0, 0, 0);
    }
    #pragma unroll
    for(int t=0;t<8;t++){
      short8 a = *(const short8*)(ab + 8192 + t*1024 + lane*16);
      acc[t] = __builtin_amdgcn_mfma_f32_32x32x16_bf16(a, bf1, acc[t], 0, 0, 0);
    }
  };

  auto epilogue = [&](const float* bias_row){
    #pragma unroll
    for(int t=0;t<8;t++){
      #pragma unroll
      for(int q=0;q<4;q++){
        f32x4 b4 = *(const f32x4*)(bias_row + 32*t + 4*hi + 8*q);
        #pragma unroll
        for(int r=0;r<4;r++){
          float vv = acc[t][4*q+r] + b4[r];
          acc[t][4*q+r] = vv > 0.f ? vv : 0.f;
        }
      }
      short8 h0, h1;
      #pragma unroll
      for(int j=0;j<8;j++){ h0[j] = f2bf(acc[t][j]); h1[j] = f2bf(acc[t][8+j]); }
      hb[2*t] = h0; hb[2*t+1] = h1;
      #pragma unroll
      for(int r=0;r<16;r++) acc[t][r] = 0.f;
    }
  };

  // tile t: 0..2 = layer0, 3..10 = layer1, 11..18 = layer2 (2 ksteps each)
  #define SRC_OF(u) ((u) < 3 ? (w0e + (u)*8192) : (u) < 11 ? (w1e + ((u)-3)*8192) \
                             : (w2e + ((u)-11)*8192))
  #define DO_TILE(T, H0, H1)                                                      \
    { if((T) < 17){ asm volatile("s_waitcnt vmcnt(2) lgkmcnt(0)" ::: "memory"); } \
      else        { asm volatile("s_waitcnt vmcnt(0) lgkmcnt(0)" ::: "memory"); } \
      __builtin_amdgcn_s_barrier();                                               \
      if((T) + 2 < 19) stage2(SRC_OF((T)+2 < 19 ? (T)+2 : 18), ((T)+2) % 3);      \
      compute2((T) % 3, H0, H1); }

  stage2(SRC_OF(0), 0);
  stage2(SRC_OF(1), 1);

  // ---- layer 0 ----
  DO_TILE(0, hb[0], hb[1])
  DO_TILE(1, hb[2], hb[3])
  DO_TILE(2, hb[4], hb[5])
  epilogue(&bias_lds[0][0]);

  // ---- layer 1 ----
  DO_TILE(3,  hb[0],  hb[1])
  DO_TILE(4,  hb[2],  hb[3])
  DO_TILE(5,  hb[4],  hb[5])
  DO_TILE(6,  hb[6],  hb[7])
  DO_TILE(7,  hb[8],  hb[9])
  DO_TILE(8,  hb[10], hb[11])
  DO_TILE(9,  hb[12], hb[13])
  DO_TILE(10, hb[14], hb[15])
  epilogue(&bias_lds[1][0]);

  // ---- layer 2 ----
  DO_TILE(11, hb[0],  hb[1])
  DO_TILE(12, hb[2],  hb[3])
  DO_TILE(13, hb[4],  hb[5])
  DO_TILE(14, hb[6],  hb[7])
  DO_TILE(15, hb[8],  hb[9])
  DO_TILE(16, hb[10], hb[11])
  DO_TILE(17, hb[12], hb[13])
  DO_TILE(18, hb[14], hb[15])
  #undef DO_TILE
  #undef SRC_OF

  // ---- output layer: bias+relu, dot with Wo, reduce hi halves ----
  float dot = 0.f;
  #pragma unroll
  for(int t=0;t<8;t++){
    #pragma unroll
    for(int q=0;q<4;q++){
      f32x4 b4 = *(const f32x4*)(&bias_lds[2][32*t + 4*hi + 8*q]);
      f32x4 w4 = *(const f32x4*)(&wo_lds[32*t + 4*hi + 8*q]);
      #pragma unroll
      for(int r=0;r<4;r++){
        float vv = acc[t][4*q+r] + b4[r];
        vv = vv > 0.f ? vv : 0.f;
        dot += vv * w4[r];
      }
    }
  }
  dot += __shfl_xor(dot, 32, 64);
  if(hi == 0 && valid) out[sid] = dot + bo_e;
}

// ---------------- KL ----------------
__global__ void k_kl(const float* __restrict__ mu_t, const float* __restrict__ lv_t,
                     const unsigned* __restrict__ counts, float* __restrict__ klout){
  __shared__ float fe[8];
  int t = threadIdx.x;
  if(t < 8){
    float s = 0.f;
    for(int i=0;i<64;i++){
      float m = mu_t[t*64+i], l = lv_t[t*64+i];
      s += 1.f + l - m*m - expf(l);
    }
    fe[t] = s;
  }
  __syncthreads();
  if(t == 0){
    float kl = 0.f;
    for(int e=0;e<8;e++) kl += fe[e] * (float)counts[e];
    klout[0] = -0.5f * kl / (float)B_N;
  }
}

extern "C" void kernel_launch(void* const* d_in, const int* in_sizes, int n_in,
                              void* d_out, int out_size, void* d_ws, size_t ws_size,
                              hipStream_t stream){
  (void)in_sizes; (void)n_in; (void)out_size; (void)ws_size;
  const float* x   = (const float*)d_in[0];
  const int*   lab = (const int*)d_in[1];
  const float* eps = (const float*)d_in[2];
  const float* mu  = (const float*)d_in[3];
  const float* lv  = (const float*)d_in[4];
  const float* W0  = (const float*)d_in[5];
  const float* b0  = (const float*)d_in[6];
  const float* Wh  = (const float*)d_in[7];
  const float* bh  = (const float*)d_in[8];
  const float* Wo  = (const float*)d_in[9];
  const float* bo  = (const float*)d_in[10];
  float* out = (float*)d_out;

  char* ws = (char*)d_ws;
  unsigned* counts = (unsigned*)(ws + 0);
  unsigned* cursor = (unsigned*)(ws + 32);
  int* te   = (int*)(ws + 128);
  int* tb   = (int*)(ws + 128 + 4*MAXT);
  int* tl   = (int*)(ws + 128 + 8*MAXT);
  int* perm = (int*)(ws + 12544);
  short* wf0 = (short*)(ws + 274688);   // 8 e x 6 ks x 8 KB = 384 KB
  short* wf1 = (short*)(ws + 667904);   // 2 layers x 8 e x 16 ks x 8 KB = 2 MB

  hipMemsetAsync(ws, 0, 64, stream);  // counts + cursor
  k_hist<<<256, 256, 0, stream>>>(lab, counts);
  k_scan<<<1, 256, 0, stream>>>(counts, cursor, te, tb, tl);
  k_scatter<<<256, 256, 0, stream>>>(lab, cursor, perm);
  k_pw<<<(24576 + 131072 + 255)/256, 256, 0, stream>>>(W0, Wh, wf0, wf1);
  k_mlp<<<MAXT, 512, 0, stream>>>(x, eps, mu, lv, b0, bh, Wo, bo,
                                  wf0, wf1, perm, te, tb, tl, out);
  k_kl<<<1, 64, 0, stream>>>(mu, lv, counts, out + B_N);
}

// Round 7
// 77.266 us; speedup vs baseline: 1.9891x; 1.0411x over previous
//
#include <hip/hip_runtime.h>
#include <hip/hip_bf16.h>
#include <stdint.h>

#define B_N 65536
#define L_N 64
#define E_N 8
#define SPB 128
#define MAXT (B_N/SPB + E_N)   // 520 max tiles

typedef __attribute__((ext_vector_type(4))) float f32x4;
typedef __attribute__((ext_vector_type(16))) float f32x16;
typedef __attribute__((ext_vector_type(8))) short short8;

__device__ __forceinline__ short f2bf(float f){
  union { float f; unsigned u; } v; v.f = f;
  unsigned r = (v.u + 0x7fffu + ((v.u >> 16) & 1u)) >> 16;  // RNE
  return (short)r;
}

// ---------------- routing ----------------
__global__ void k_hist(const int* __restrict__ labels, unsigned* __restrict__ counts){
  __shared__ unsigned lc[8];
  if(threadIdx.x < 8) lc[threadIdx.x] = 0;
  __syncthreads();
  int i = blockIdx.x * blockDim.x + threadIdx.x;
  if(i < B_N) atomicAdd(&lc[labels[i] & 7], 1u);
  __syncthreads();
  if(threadIdx.x < 8 && lc[threadIdx.x]) atomicAdd(&counts[threadIdx.x], lc[threadIdx.x]);
}

__global__ void k_scan(const unsigned* __restrict__ counts, unsigned* __restrict__ cursor,
                       int* __restrict__ te, int* __restrict__ tb, int* __restrict__ tl){
  __shared__ int off[9], ts[9];
  if(threadIdx.x == 0){
    int o = 0, t = 0;
    for(int e=0;e<8;e++){
      off[e] = o; ts[e] = t;
      o += (int)counts[e];
      t += ((int)counts[e] + SPB - 1) / SPB;
    }
    off[8] = o; ts[8] = t;
    for(int e=0;e<8;e++) cursor[e] = (unsigned)off[e];
  }
  __syncthreads();
  for(int i = threadIdx.x; i < MAXT; i += blockDim.x){
    if(i < ts[8]){
      int e = 0;
      while(e < 7 && i >= ts[e+1]) e++;
      te[i] = e;
      tb[i] = off[e] + (i - ts[e]) * SPB;
      tl[i] = off[e] + (int)counts[e];
    } else { te[i] = 0; tb[i] = 0; tl[i] = 0; }
  }
}

__global__ void k_scatter(const int* __restrict__ labels, unsigned* __restrict__ cursor,
                          int* __restrict__ perm){
  __shared__ unsigned lcnt[8], lbase[8];
  if(threadIdx.x < 8) lcnt[threadIdx.x] = 0;
  __syncthreads();
  int i = blockIdx.x * blockDim.x + threadIdx.x;
  int e = 0; unsigned r = 0;
  if(i < B_N){ e = labels[i] & 7; r = atomicAdd(&lcnt[e], 1u); }
  __syncthreads();
  if(threadIdx.x < 8 && lcnt[threadIdx.x])
    lbase[threadIdx.x] = atomicAdd(&cursor[threadIdx.x], lcnt[threadIdx.x]);
  __syncthreads();
  if(i < B_N) perm[lbase[e] + r] = i;
}

// ---------------- weight fragment prep (32x32x16 A-frags) ----------------
// per (expert, kstep16): [t 0..7][lane 0..63][j 0..7] bf16 (16B/lane)
// A elem (lane l, j): m = 32t + (l&31); k = 16s + 4*(l>>5) + (j&3) + 8*(j>>2)
// layer 0 padded to 6 ksteps (K=96), zeros beyond k=66
__global__ void k_pw(const float* __restrict__ W0, const float* __restrict__ Wh,
                     short* __restrict__ wf0, short* __restrict__ wf1){
  int uid = blockIdx.x * blockDim.x + threadIdx.x;
  const int NU0 = 8*6*8*64;        // 24576
  const int NU1 = 2*8*16*8*64;     // 131072
  if(uid < NU0){
    int e = uid / 3072, r = uid % 3072;
    int s = r / 512, r2 = r % 512, t = r2 / 64, l = r2 % 64;
    int hi = l >> 5, m = 32*t + (l & 31);
    short8 v;
    #pragma unroll
    for(int j=0;j<8;j++){
      int k = 16*s + 4*hi + (j & 3) + 8*(j >> 2);
      float f = (k < 67) ? W0[(e*67 + k)*256 + m] : 0.f;
      v[j] = f2bf(f);
    }
    *(short8*)(wf0 + (size_t)uid * 8) = v;
  } else if(uid < NU0 + NU1){
    int u = uid - NU0;
    int le = u / 8192, r1 = u % 8192;           // le = lh*8 + e
    int s = r1 / 512, r2 = r1 % 512, t = r2 / 64, l = r2 % 64;
    int hi = l >> 5, m = 32*t + (l & 31);
    short8 v;
    #pragma unroll
    for(int j=0;j<8;j++){
      int k = 16*s + 4*hi + (j & 3) + 8*(j >> 2);
      v[j] = f2bf(Wh[((size_t)le*256 + k)*256 + m]);
    }
    *(short8*)(wf1 + (size_t)u * 8) = v;
  }
}

// -------- fused MoE MLP: 128 samples/block, 4 waves, 2 blocks/CU co-resident --------
__global__ __launch_bounds__(256, 2) void k_mlp(
    const float* __restrict__ x, const float* __restrict__ eps,
    const float* __restrict__ mu_t, const float* __restrict__ lv_t,
    const float* __restrict__ b0, const float* __restrict__ bh,
    const float* __restrict__ Wo, const float* __restrict__ bo,
    const short* __restrict__ wf0, const short* __restrict__ wf1,
    const int* __restrict__ perm, const int* __restrict__ te,
    const int* __restrict__ tb, const int* __restrict__ tl,
    float* __restrict__ out)
{
  __shared__ __align__(16) short abuf[3][8192];   // 3 x 16KB A-tile (2 ksteps each)
  __shared__ __align__(16) float bias_lds[3][256];
  __shared__ __align__(16) float wo_lds[256];

  const int tid  = threadIdx.x;
  const int w    = tid >> 6, lane = tid & 63;
  const int hi   = lane >> 5, col = lane & 31;
  const int bid  = blockIdx.x;
  const int e = te[bid], base = tb[bid], lim = tl[bid];
  if(base >= lim) return;

  bias_lds[0][tid] = b0[e*256 + tid];
  bias_lds[1][tid] = bh[e*256 + tid];
  bias_lds[2][tid] = bh[(8 + e)*256 + tid];
  wo_lds[tid]      = Wo[e*256 + tid];

  const int pos = base + w*32 + col;      // each of 4 waves owns 32 samples
  const bool valid = pos < lim;
  const int sid = perm[valid ? pos : (lim - 1)];
  const float bo_e = bo[e];

  // ---- layer-0 B-fragments (x_in^T), K=96 padded, into hb[0..5] ----
  short8 hb[16];
  #pragma unroll
  for(int s=0;s<6;s++){
    short8 v;
    #pragma unroll
    for(int j=0;j<8;j++){
      int k = 16*s + 4*hi + (j & 3) + 8*(j >> 2);
      float f = 0.f;
      if(k < 3) f = x[sid*3 + k];
      else if(k < 67){
        int zi = k - 3;
        f = mu_t[e*64 + zi] + eps[(size_t)sid*64 + zi] * __expf(0.5f * lv_t[e*64 + zi]);
      }
      v[j] = f2bf(f);
    }
    hb[s] = v;
  }
  #pragma unroll
  for(int s=6;s<16;s++) hb[s] = short8{0,0,0,0,0,0,0,0};

  const short* w0e = wf0 + (size_t)e * (6*4096);
  const short* w1e = wf1 + (size_t)(0*8 + e) * (16*4096);
  const short* w2e = wf1 + (size_t)(1*8 + e) * (16*4096);

  f32x16 acc[8];
  #pragma unroll
  for(int t=0;t<8;t++)
    #pragma unroll
    for(int r=0;r<16;r++) acc[t][r] = 0.f;

  // stage one 16KB tile (2 ksteps): 4 x global_load_lds(16B) per thread
  auto stage2 = [&](const short* srcT, int bufidx){
    #pragma unroll
    for(int c=0;c<4;c++){
      const char* gp = (const char*)srcT + c*4096 + tid*16;          // per-lane src
      char* lp = (char*)&abuf[bufidx][0] + c*4096 + w*1024;          // wave-uniform dst
      __builtin_amdgcn_global_load_lds((const __attribute__((address_space(1))) void*)gp,
                                       (__attribute__((address_space(3))) void*)lp, 16, 0, 0);
    }
  };

  // compute one tile: 2 ksteps x 8 feature-tiles
  auto compute2 = [&](int bufidx, short8 bf0, short8 bf1){
    const char* ab = (const char*)&abuf[bufidx][0];
    #pragma unroll
    for(int t=0;t<8;t++){
      short8 a = *(const short8*)(ab + t*1024 + lane*16);
      acc[t] = __builtin_amdgcn_mfma_f32_32x32x16_bf16(a, bf0, acc[t], 0, 0, 0);
    }
    #pragma unroll
    for(int t=0;t<8;t++){
      short8 a = *(const short8*)(ab + 8192 + t*1024 + lane*16);
      acc[t] = __builtin_amdgcn_mfma_f32_32x32x16_bf16(a, bf1, acc[t], 0, 0, 0);
    }
  };

  auto epilogue = [&](const float* bias_row){
    #pragma unroll
    for(int t=0;t<8;t++){
      #pragma unroll
      for(int q=0;q<4;q++){
        f32x4 b4 = *(const f32x4*)(bias_row + 32*t + 4*hi + 8*q);
        #pragma unroll
        for(int r=0;r<4;r++){
          float vv = acc[t][4*q+r] + b4[r];
          acc[t][4*q+r] = vv > 0.f ? vv : 0.f;
        }
      }
      short8 h0, h1;
      #pragma unroll
      for(int j=0;j<8;j++){ h0[j] = f2bf(acc[t][j]); h1[j] = f2bf(acc[t][8+j]); }
      hb[2*t] = h0; hb[2*t+1] = h1;
      #pragma unroll
      for(int r=0;r<16;r++) acc[t][r] = 0.f;
    }
  };

  // tile t: 0..2 = layer0, 3..10 = layer1, 11..18 = layer2 (2 ksteps each)
  #define SRC_OF(u) ((u) < 3 ? (w0e + (u)*8192) : (u) < 11 ? (w1e + ((u)-3)*8192) \
                             : (w2e + ((u)-11)*8192))
  #define DO_TILE(T, H0, H1)                                                      \
    { if((T) < 17){ asm volatile("s_waitcnt vmcnt(4) lgkmcnt(0)" ::: "memory"); } \
      else        { asm volatile("s_waitcnt vmcnt(0) lgkmcnt(0)" ::: "memory"); } \
      __builtin_amdgcn_s_barrier();                                               \
      if((T) + 2 < 19) stage2(SRC_OF((T)+2 < 19 ? (T)+2 : 18), ((T)+2) % 3);      \
      compute2((T) % 3, H0, H1); }

  stage2(SRC_OF(0), 0);
  stage2(SRC_OF(1), 1);

  // ---- layer 0 ----
  DO_TILE(0, hb[0], hb[1])
  DO_TILE(1, hb[2], hb[3])
  DO_TILE(2, hb[4], hb[5])
  epilogue(&bias_lds[0][0]);

  // ---- layer 1 ----
  DO_TILE(3,  hb[0],  hb[1])
  DO_TILE(4,  hb[2],  hb[3])
  DO_TILE(5,  hb[4],  hb[5])
  DO_TILE(6,  hb[6],  hb[7])
  DO_TILE(7,  hb[8],  hb[9])
  DO_TILE(8,  hb[10], hb[11])
  DO_TILE(9,  hb[12], hb[13])
  DO_TILE(10, hb[14], hb[15])
  epilogue(&bias_lds[1][0]);

  // ---- layer 2 ----
  DO_TILE(11, hb[0],  hb[1])
  DO_TILE(12, hb[2],  hb[3])
  DO_TILE(13, hb[4],  hb[5])
  DO_TILE(14, hb[6],  hb[7])
  DO_TILE(15, hb[8],  hb[9])
  DO_TILE(16, hb[10], hb[11])
  DO_TILE(17, hb[12], hb[13])
  DO_TILE(18, hb[14], hb[15])
  #undef DO_TILE
  #undef SRC_OF

  // ---- output layer: bias+relu, dot with Wo, reduce hi halves ----
  float dot = 0.f;
  #pragma unroll
  for(int t=0;t<8;t++){
    #pragma unroll
    for(int q=0;q<4;q++){
      f32x4 b4 = *(const f32x4*)(&bias_lds[2][32*t + 4*hi + 8*q]);
      f32x4 w4 = *(const f32x4*)(&wo_lds[32*t + 4*hi + 8*q]);
      #pragma unroll
      for(int r=0;r<4;r++){
        float vv = acc[t][4*q+r] + b4[r];
        vv = vv > 0.f ? vv : 0.f;
        dot += vv * w4[r];
      }
    }
  }
  dot += __shfl_xor(dot, 32, 64);
  if(hi == 0 && valid) out[sid] = dot + bo_e;
}

// ---------------- KL ----------------
__global__ void k_kl(const float* __restrict__ mu_t, const float* __restrict__ lv_t,
                     const unsigned* __restrict__ counts, float* __restrict__ klout){
  __shared__ float fe[8];
  int t = threadIdx.x;
  if(t < 8){
    float s = 0.f;
    for(int i=0;i<64;i++){
      float m = mu_t[t*64+i], l = lv_t[t*64+i];
      s += 1.f + l - m*m - expf(l);
    }
    fe[t] = s;
  }
  __syncthreads();
  if(t == 0){
    float kl = 0.f;
    for(int e=0;e<8;e++) kl += fe[e] * (float)counts[e];
    klout[0] = -0.5f * kl / (float)B_N;
  }
}

extern "C" void kernel_launch(void* const* d_in, const int* in_sizes, int n_in,
                              void* d_out, int out_size, void* d_ws, size_t ws_size,
                              hipStream_t stream){
  (void)in_sizes; (void)n_in; (void)out_size; (void)ws_size;
  const float* x   = (const float*)d_in[0];
  const int*   lab = (const int*)d_in[1];
  const float* eps = (const float*)d_in[2];
  const float* mu  = (const float*)d_in[3];
  const float* lv  = (const float*)d_in[4];
  const float* W0  = (const float*)d_in[5];
  const float* b0  = (const float*)d_in[6];
  const float* Wh  = (const float*)d_in[7];
  const float* bh  = (const float*)d_in[8];
  const float* Wo  = (const float*)d_in[9];
  const float* bo  = (const float*)d_in[10];
  float* out = (float*)d_out;

  char* ws = (char*)d_ws;
  unsigned* counts = (unsigned*)(ws + 0);
  unsigned* cursor = (unsigned*)(ws + 32);
  int* te   = (int*)(ws + 128);
  int* tb   = (int*)(ws + 128 + 4*MAXT);
  int* tl   = (int*)(ws + 128 + 8*MAXT);
  int* perm = (int*)(ws + 12544);
  short* wf0 = (short*)(ws + 274688);   // 8 e x 6 ks x 8 KB = 384 KB
  short* wf1 = (short*)(ws + 667904);   // 2 layers x 8 e x 16 ks x 8 KB = 2 MB

  hipMemsetAsync(ws, 0, 64, stream);  // counts + cursor
  k_hist<<<256, 256, 0, stream>>>(lab, counts);
  k_scan<<<1, 256, 0, stream>>>(counts, cursor, te, tb, tl);
  k_scatter<<<256, 256, 0, stream>>>(lab, cursor, perm);
  k_pw<<<(24576 + 131072 + 255)/256, 256, 0, stream>>>(W0, Wh, wf0, wf1);
  k_mlp<<<MAXT, 256, 0, stream>>>(x, eps, mu, lv, b0, bh, Wo, bo,
                                  wf0, wf1, perm, te, tb, tl, out);
  k_kl<<<1, 64, 0, stream>>>(mu, lv, counts, out + B_N);
}